// Round 12
// baseline (97.865 us; speedup 1.0000x reference)
//
#include <hip/hip_runtime.h>
#include <hip/hip_bf16.h>

// Masked SDPA, B=16, NQ=2048, NKV=2048, D=64, f32 in/out, bf16 MFMA compute.
// R12: XCD-affine work queues. R11's single global queue balanced work but
// destroyed per-XCD L2 locality (FETCH 6.2->34.8 MB: every XCD pulled the
// whole 8MB K/V image). Fix: (1) scheduler kernel sorts batches by work and
// pairs rank i with 15-i -> XCD x owns 2 batches (~equal work per XCD);
// (2) blocks read their physical XCD via s_getreg(HW_REG_XCC_ID) and pull
// from an XCD-local queue (128 items = 2 batches x 64 32-q-tiles) -> L2
// working set ~4MB/XCD; (3) work-stealing sweep over other queues when local
// drains -> correctness independent of XCC mapping, residual imbalance
// absorbed. Wave body/merge/prep verbatim from R11 (passing): reg-direct
// fragment loads, 32x32 swapped QK^T, in-reg P (cvt_pk+permlane32), T13.

typedef __attribute__((ext_vector_type(8))) short short8;
typedef __attribute__((ext_vector_type(4))) short short4v;
typedef __attribute__((ext_vector_type(4))) float float4v;
typedef __attribute__((ext_vector_type(16))) float f32x16;

#define BATCH 16
#define NQ 2048
#define NKV 2048
#define DH 64
#define KVB 64
#define NTILES (NKV / KVB)          // 32
#define TILE_ELEMS (KVB * DH)       // 4096 bf16 = 8 KB per tile per array
#define NITEMS_X 128                // per-XCD items: 2 batches x 64 q-tiles
#define NEG_INF -1e20f
// (1/sqrt(64)) * log2(e)
#define SCALE_LOG2 0.180336880111120f

__device__ __forceinline__ short f2bf(float x) {
    union { float f; unsigned u; } v; v.f = x;
    unsigned r = (v.u + 0x7fffu + ((v.u >> 16) & 1u)) >> 16;
    return (short)r;
}

__device__ __forceinline__ short8 cvt8(float4v a, float4v b) {
    short8 r;
    r[0] = f2bf(a[0]); r[1] = f2bf(a[1]); r[2] = f2bf(a[2]); r[3] = f2bf(a[3]);
    r[4] = f2bf(b[0]); r[5] = f2bf(b[1]); r[6] = f2bf(b[2]); r[7] = f2bf(b[3]);
    return r;
}

// ---- scheduler: sort batches by work, pair i with 15-i per XCD, zero ctrs --
__global__ void sched_kernel(const int* __restrict__ vl,
                             int* __restrict__ xb, int* __restrict__ ctrs)
{
    if (threadIdx.x == 0) {
        int t[BATCH], idx[BATCH];
        for (int i = 0; i < BATCH; ++i) {
            const int v  = vl[i];
            const int nk = (v == 0) ? NKV : v;
            t[i] = (nk + KVB - 1) / KVB;
            idx[i] = i;
        }
        for (int i = 1; i < BATCH; ++i) {       // insertion sort desc by t
            const int ti = t[i], ii = idx[i];
            int j = i - 1;
            while (j >= 0 && t[j] < ti) { t[j+1] = t[j]; idx[j+1] = idx[j]; --j; }
            t[j+1] = ti; idx[j+1] = ii;
        }
        for (int x = 0; x < 8; ++x) {
            xb[2 * x]     = idx[x];             // heavy batch
            xb[2 * x + 1] = idx[15 - x];        // light batch
            ctrs[x] = 0;
        }
    }
}

// ---- prep: f32 -> bf16 fragment-sequential layouts (unchanged) -------------
__global__ __launch_bounds__(256) void prep_kernel(
    const float* __restrict__ K, const float* __restrict__ V,
    const int* __restrict__ valid_lens,
    short* __restrict__ Kf, short* __restrict__ Vf)
{
    const int b    = blockIdx.x >> 5;
    const int tile = blockIdx.x & 31;
    const int vlen = valid_lens[b];
    const int nkv  = (vlen == 0) ? NKV : vlen;
    if (tile * KVB >= nkv) return;          // never read by attn

    const int tid = threadIdx.x;
    const int ln  = tid & 63;
    const int l31 = ln & 31;
    const int hi8 = (ln >> 5) * 8;
    const size_t gbase = ((size_t)b * NKV + (size_t)tile * KVB) * DH;
    short* kt = Kf + (((size_t)b * NTILES + tile) * TILE_ELEMS);
    short* vt = Vf + (((size_t)b * NTILES + tile) * TILE_ELEMS);

#pragma unroll
    for (int s = 0; s < 2; ++s) {           // K frags: slots s*256+tid
        const int kk = tid >> 6;            // 0..3
        const int kv = s * 32 + l31;
        const int d  = kk * 16 + hi8;
        const float* p = K + gbase + (size_t)kv * DH + d;
        *reinterpret_cast<short8*>(kt + (s * 256 + tid) * 8) =
            cvt8(*reinterpret_cast<const float4v*>(p),
                 *reinterpret_cast<const float4v*>(p + 4));
    }
    {   // V: 4x4 float4 transpose -> short4 writes into frag-sequential layout
        const int kv0 = (tid >> 4) << 2;    // 0..60 step 4
        const int d0  = (tid & 15) << 2;    // 0..60 step 4
        const float* p = V + gbase + (size_t)kv0 * DH + d0;
        float4v r0 = *reinterpret_cast<const float4v*>(p);
        float4v r1 = *reinterpret_cast<const float4v*>(p + DH);
        float4v r2 = *reinterpret_cast<const float4v*>(p + 2 * DH);
        float4v r3 = *reinterpret_cast<const float4v*>(p + 3 * DH);
        const int ks  = kv0 >> 4;
        const int hiv = (kv0 >> 3) & 1;
        const int j0  = kv0 & 7;            // 0 or 4
#pragma unroll
        for (int k = 0; k < 4; ++k) {
            const int d    = d0 + k;
            const int lanev = (d & 31) + 32 * hiv;
            short4v w;
            w[0] = f2bf(r0[k]); w[1] = f2bf(r1[k]);
            w[2] = f2bf(r2[k]); w[3] = f2bf(r3[k]);
            *reinterpret_cast<short4v*>(
                vt + (((d >> 5) * 4 + ks) * 64 + lanev) * 8 + j0) = w;
        }
    }
}

// ------ attn: persistent 8-wave blocks; XCD-local queues + stealing ---------
__global__ __launch_bounds__(512) void attn_fwd_kernel(
    const float* __restrict__ Q,
    const short* __restrict__ Kf,
    const short* __restrict__ Vf,
    const int* __restrict__ valid_lens,
    float* __restrict__ O,
    const int* __restrict__ xb,
    int* __restrict__ ctrs)
{
    __shared__ float  mrg[8][32][68];      // [kvw][q][d] pad 68 (~69.6 KB)
    __shared__ float2 mlb[8][32];
    __shared__ int s_item;

    const int tid  = threadIdx.x;
    const int kvw  = tid >> 6;             // KV eighth (= wave)
    const int lane = tid & 63;
    const int l31  = lane & 31;
    const int hi   = lane >> 5;

    int myx;
    asm volatile("s_getreg_b32 %0, hwreg(HW_REG_XCC_ID)" : "=s"(myx));
    myx &= 7;

    for (int dq = 0; dq < 8; ++dq) {       // own queue first, then steal
        const int qx = (myx + dq) & 7;
        for (;;) {
            if (tid == 0) s_item = atomicAdd(&ctrs[qx], 1);
            __syncthreads();               // publish s_item (+ fence mrg reuse)
            const int item = s_item;
            __syncthreads();               // protect s_item from next write
            if (item >= NITEMS_X) break;

            const int b     = xb[2 * qx + (item & 1)];
            const int qbase = (item >> 1) * 32;

            const int vlen  = valid_lens[b];
            const int nkv   = (vlen == 0) ? NKV : vlen;
            const int tiles = (nkv + KVB - 1) / KVB;
            const int nh    = (tiles - kvw + 7) >> 3;   // my eighth (stride 8)

            // Q B-fragments (scale folded): lane col q=l31, k d=kk*16+hi*8+j
            const float* Qb = Q + ((size_t)b * NQ + qbase + l31) * DH;
            short8 qfrag[4];
#pragma unroll
            for (int kk = 0; kk < 4; ++kk) {
                const float* p = Qb + kk * 16 + hi * 8;
                float4v a = *reinterpret_cast<const float4v*>(p);
                float4v c = *reinterpret_cast<const float4v*>(p + 4);
#pragma unroll
                for (int j = 0; j < 4; ++j) { a[j] *= SCALE_LOG2; c[j] *= SCALE_LOG2; }
                qfrag[kk] = cvt8(a, c);
            }

            const short* Kfb = Kf + (size_t)b * NTILES * TILE_ELEMS + lane * 8;
            const short* Vfb = Vf + (size_t)b * NTILES * TILE_ELEMS + lane * 8;

            auto load_k = [&](short8 (&kf)[8], int tile) {
                const short* p = Kfb + (size_t)tile * TILE_ELEMS;
#pragma unroll
                for (int i = 0; i < 8; ++i)
                    kf[i] = *reinterpret_cast<const short8*>(p + i * 512);
            };
            auto load_v = [&](short8 (&vf)[8], int tile) {
                const short* p = Vfb + (size_t)tile * TILE_ELEMS;
#pragma unroll
                for (int i = 0; i < 8; ++i)
                    vf[i] = *reinterpret_cast<const short8*>(p + i * 512);
            };

            f32x16 acc_o[2];
#pragma unroll
            for (int t = 0; t < 2; ++t)
#pragma unroll
                for (int r = 0; r < 16; ++r) acc_o[t][r] = 0.f;
            float m = -INFINITY, lsum = 0.f;

            short8 kf0[8], kf1[8], vfr[8];

            auto body = [&](short8 (&kc)[8], short8 (&kn)[8], int it) {
                const int tile = 8 * it + kvw;
                load_v(vfr, tile);         // issue early; used after softmax

                // ---- S^T = K Q^T: lane owns q=l31, kv=32s+(r&3)+8(r>>2)+4hi
                f32x16 acs[2];
#pragma unroll
                for (int s = 0; s < 2; ++s)
#pragma unroll
                    for (int r = 0; r < 16; ++r) acs[s][r] = 0.f;
                __builtin_amdgcn_s_setprio(1);
#pragma unroll
                for (int s = 0; s < 2; ++s)
#pragma unroll
                    for (int kk = 0; kk < 4; ++kk)
                        acs[s] = __builtin_amdgcn_mfma_f32_32x32x16_bf16(
                            kc[s * 4 + kk], qfrag[kk], acs[s], 0, 0, 0);
                __builtin_amdgcn_s_setprio(0);

                if (it + 1 < nh) load_k(kn, 8 * (it + 1) + kvw);  // prefetch

                // ---- mask, skipped for fully-valid tiles ----
                if (vlen < (tile + 1) * KVB) {
                    const int kvb0 = tile * KVB + 4 * hi;
#pragma unroll
                    for (int s = 0; s < 2; ++s) {
                        const int vlim = vlen - (kvb0 + s * 32);
#pragma unroll
                        for (int r = 0; r < 16; ++r) {
                            const int rc = (r & 3) + 8 * (r >> 2);
                            acs[s][r] = (rc < vlim) ? acs[s][r] : NEG_INF;
                        }
                    }
                }

                // ---- row max: depth-5 tree + 1 shuffle ----
                float mx[8];
#pragma unroll
                for (int r = 0; r < 8; ++r)
                    mx[r] = fmaxf(fmaxf(acs[0][r], acs[0][r + 8]),
                                  fmaxf(acs[1][r], acs[1][r + 8]));
#pragma unroll
                for (int d = 4; d; d >>= 1)
#pragma unroll
                    for (int r = 0; r < d; ++r) mx[r] = fmaxf(mx[r], mx[r + d]);
                float x = mx[0];
                x = fmaxf(x, __shfl_xor(x, 32, 64));

                // ---- T13 defer-max ----
                float mn = m;
                if (!__all(x <= m + 8.f)) {
                    mn = fmaxf(m, x);
                    const float alpha = exp2f(m - mn);   // m=-inf first -> 0
                    m = mn;
                    lsum *= alpha;
#pragma unroll
                    for (int r = 0; r < 16; ++r) {
                        const int rc = (r & 3) + 8 * (r >> 2);
                        const float ar = __shfl(alpha, rc + 4 * hi, 64);
                        acc_o[0][r] *= ar;
                        acc_o[1][r] *= ar;
                    }
                }

                // ---- P = exp2(s - mn); sum as tree + 1 shuffle ----
#pragma unroll
                for (int s = 0; s < 2; ++s)
#pragma unroll
                    for (int r = 0; r < 16; ++r) acs[s][r] = exp2f(acs[s][r] - mn);
                float sm[8];
#pragma unroll
                for (int r = 0; r < 8; ++r)
                    sm[r] = (acs[0][r] + acs[0][r + 8]) + (acs[1][r] + acs[1][r + 8]);
#pragma unroll
                for (int d = 4; d; d >>= 1)
#pragma unroll
                    for (int r = 0; r < d; ++r) sm[r] += sm[r + d];
                float rs = sm[0];
                rs += __shfl_xor(rs, 32, 64);
                lsum += rs;

                // ---- P -> bf16 packs (16 cvt_pk) ----
                unsigned pk[2][4][2];
#pragma unroll
                for (int s = 0; s < 2; ++s)
#pragma unroll
                    for (int be = 0; be < 4; ++be)
#pragma unroll
                        for (int c = 0; c < 2; ++c)
                            asm("v_cvt_pk_bf16_f32 %0, %1, %2"
                                : "=v"(pk[s][be][c])
                                : "v"(acs[s][4 * be + 2 * c]),
                                  "v"(acs[s][4 * be + 2 * c + 1]));

                // ---- O += P V: 8 permlane32_swap build A-frags ----
                __builtin_amdgcn_s_setprio(1);
#pragma unroll
                for (int ks = 0; ks < 4; ++ks) {
                    const int s = ks >> 1, g = ks & 1;
                    unsigned w0 = pk[s][2 * g][0], w2 = pk[s][2 * g + 1][0];
                    unsigned w1 = pk[s][2 * g][1], w3 = pk[s][2 * g + 1][1];
                    asm("v_permlane32_swap_b32 %0, %1" : "+v"(w0), "+v"(w2));
                    asm("v_permlane32_swap_b32 %0, %1" : "+v"(w1), "+v"(w3));
                    union { unsigned u[4]; short8 s8; } pf;
                    pf.u[0] = w0; pf.u[1] = w1; pf.u[2] = w2; pf.u[3] = w3;
#pragma unroll
                    for (int t = 0; t < 2; ++t)
                        acc_o[t] = __builtin_amdgcn_mfma_f32_32x32x16_bf16(
                            pf.s8, vfr[t * 4 + ks], acc_o[t], 0, 0, 0);
                }
                __builtin_amdgcn_s_setprio(0);
            };

            if (nh > 0) load_k(kf0, kvw);
            int it = 0;
            for (; it + 1 < nh; it += 2) { // 2-phase unroll: static reg bufs
                body(kf0, kf1, it);
                body(kf1, kf0, it + 1);
            }
            if (it < nh) body(kf0, kf1, it);

            // ---- 8-way merge across KV eighths (shuffle-free) ----
#pragma unroll
            for (int t = 0; t < 2; ++t)
#pragma unroll
                for (int r = 0; r < 16; ++r) {
                    const int rc = (r & 3) + 8 * (r >> 2);
                    mrg[kvw][rc + 4 * hi][t * 32 + l31] = acc_o[t][r];
                }
            if (lane < 32) mlb[kvw][l31] = float2{m, lsum};
            __syncthreads();

            // epilogue: 512 threads; thread -> (row = tid>>4, 4 cols)
            {
                const int row = tid >> 4;
                const int dg  = (tid & 15) << 2;
                float mi[8], li[8];
                float M = -INFINITY;
#pragma unroll
                for (int i = 0; i < 8; ++i) {
                    const float2 c = mlb[i][row];
                    mi[i] = c.x; li[i] = c.y;
                    if (li[i] > 0.f) M = fmaxf(M, mi[i]);
                }
                float wgt[8], L = 0.f;
#pragma unroll
                for (int i = 0; i < 8; ++i) {
                    wgt[i] = (li[i] > 0.f) ? exp2f(mi[i] - M) : 0.f;
                    L += li[i] * wgt[i];
                }
                const float Linv = 1.f / L;
                float4v o = {0.f, 0.f, 0.f, 0.f};
#pragma unroll
                for (int i = 0; i < 8; ++i) {
                    if (li[i] > 0.f) {
                        float4v a = *reinterpret_cast<const float4v*>(&mrg[i][row][dg]);
#pragma unroll
                        for (int j = 0; j < 4; ++j) o[j] += a[j] * wgt[i];
                    }
                }
#pragma unroll
                for (int j = 0; j < 4; ++j) o[j] *= Linv;
                *reinterpret_cast<float4v*>(
                    O + ((size_t)b * NQ + qbase + row) * DH + dg) = o;
            }
            // next pull's __syncthreads fences mrg reuse
        }
    }
}

extern "C" void kernel_launch(void* const* d_in, const int* in_sizes, int n_in,
                              void* d_out, int out_size, void* d_ws, size_t ws_size,
                              hipStream_t stream) {
    const float* Q = (const float*)d_in[0];
    const float* K = (const float*)d_in[1];
    const float* V = (const float*)d_in[2];
    const int* vl  = (const int*)d_in[3];
    float* Out     = (float*)d_out;

    short* Kws = (short*)d_ws;
    short* Vws = Kws + (size_t)BATCH * NTILES * TILE_ELEMS;
    int*   xb   = (int*)((char*)d_ws + (8u << 20));   // 16 ints
    int*   ctrs = xb + 16;                            // 8 ints

    sched_kernel<<<dim3(1), dim3(64), 0, stream>>>(vl, xb, ctrs);
    prep_kernel<<<dim3(BATCH * NTILES), dim3(256), 0, stream>>>(K, V, vl, Kws, Vws);
    attn_fwd_kernel<<<dim3(512), dim3(512), 0, stream>>>(
        Q, Kws, Vws, vl, Out, xb, ctrs);
}

// Round 13
// 35.085 us; speedup vs baseline: 2.7893x; 2.7893x over previous
//
#include <hip/hip_runtime.h>
#include <hip/hip_bf16.h>

// Masked SDPA, B=16, NQ=2048, NKV=2048, D=64, f32 in/out, bf16 MFMA compute.
// R13: break the PV accumulator dependency chain. Invariant across R7-R12:
// ~5700 cy per 64-kv iteration regardless of staging/barriers/balance =>
// the serial MFMA C-in->C-out chain (64 dependent 32x32 MFMAs over 16 tiles
// x ~90cy dependent latency) is the floor. Fix: TWO independent accumulator
// sets (even/odd tiles, same running-max scale, plain add at end) + body-
// local V fragments (no false cross-tile reuse dep) + raw v_exp_f32.
// Rest verbatim from R9 (best measured): static grid 256 (1 block/CU),
// 8 waves = 4 qsub(32q) x 2 kv-halves, reg-direct fragment-sequential loads
// from ws, swapped 32x32 QK^T, in-register P (cvt_pk + permlane32_swap),
// T13 defer-max, K-prefetch reg double-buffer, LDS merge epilogue.

typedef __attribute__((ext_vector_type(8))) short short8;
typedef __attribute__((ext_vector_type(4))) short short4v;
typedef __attribute__((ext_vector_type(4))) float float4v;
typedef __attribute__((ext_vector_type(16))) float f32x16;

#define BATCH 16
#define NQ 2048
#define NKV 2048
#define DH 64
#define KVB 64
#define NTILES (NKV / KVB)          // 32
#define TILE_ELEMS (KVB * DH)       // 4096 bf16 = 8 KB per tile per array
#define NEG_INF -1e20f
// (1/sqrt(64)) * log2(e)
#define SCALE_LOG2 0.180336880111120f

__device__ __forceinline__ short f2bf(float x) {
    union { float f; unsigned u; } v; v.f = x;
    unsigned r = (v.u + 0x7fffu + ((v.u >> 16) & 1u)) >> 16;
    return (short)r;
}

__device__ __forceinline__ short8 cvt8(float4v a, float4v b) {
    short8 r;
    r[0] = f2bf(a[0]); r[1] = f2bf(a[1]); r[2] = f2bf(a[2]); r[3] = f2bf(a[3]);
    r[4] = f2bf(b[0]); r[5] = f2bf(b[1]); r[6] = f2bf(b[2]); r[7] = f2bf(b[3]);
    return r;
}

// raw 2^x (we work in log2 domain throughout)
__device__ __forceinline__ float fexp2(float x) {
    float r; asm("v_exp_f32 %0, %1" : "=v"(r) : "v"(x)); return r;
}

// ---- prep: f32 -> bf16 fragment-sequential layouts (unchanged) -------------
// Kf[b][tile][(s*4+kk)*64+lane]*8 : lane(l31,hi) = K[kv=s*32+l31][d=kk*16+hi*8+j]
// Vf[b][tile][(t*4+ks)*64+lane]*8 : lane(l31,hi) = V^T[d=t*32+l31][kv=ks*16+hi*8+j]
__global__ __launch_bounds__(256) void prep_kernel(
    const float* __restrict__ K, const float* __restrict__ V,
    const int* __restrict__ valid_lens,
    short* __restrict__ Kf, short* __restrict__ Vf)
{
    const int b    = blockIdx.x >> 5;
    const int tile = blockIdx.x & 31;
    const int vlen = valid_lens[b];
    const int nkv  = (vlen == 0) ? NKV : vlen;
    if (tile * KVB >= nkv) return;          // never read by attn

    const int tid = threadIdx.x;
    const int ln  = tid & 63;
    const int l31 = ln & 31;
    const int hi8 = (ln >> 5) * 8;
    const size_t gbase = ((size_t)b * NKV + (size_t)tile * KVB) * DH;
    short* kt = Kf + (((size_t)b * NTILES + tile) * TILE_ELEMS);
    short* vt = Vf + (((size_t)b * NTILES + tile) * TILE_ELEMS);

#pragma unroll
    for (int s = 0; s < 2; ++s) {           // K frags: slots s*256+tid
        const int kk = tid >> 6;            // 0..3
        const int kv = s * 32 + l31;
        const int d  = kk * 16 + hi8;
        const float* p = K + gbase + (size_t)kv * DH + d;
        *reinterpret_cast<short8*>(kt + (s * 256 + tid) * 8) =
            cvt8(*reinterpret_cast<const float4v*>(p),
                 *reinterpret_cast<const float4v*>(p + 4));
    }
    {   // V: 4x4 float4 transpose -> short4 writes into frag-sequential layout
        const int kv0 = (tid >> 4) << 2;    // 0..60 step 4
        const int d0  = (tid & 15) << 2;    // 0..60 step 4
        const float* p = V + gbase + (size_t)kv0 * DH + d0;
        float4v r0 = *reinterpret_cast<const float4v*>(p);
        float4v r1 = *reinterpret_cast<const float4v*>(p + DH);
        float4v r2 = *reinterpret_cast<const float4v*>(p + 2 * DH);
        float4v r3 = *reinterpret_cast<const float4v*>(p + 3 * DH);
        const int ks  = kv0 >> 4;
        const int hiv = (kv0 >> 3) & 1;
        const int j0  = kv0 & 7;            // 0 or 4
#pragma unroll
        for (int k = 0; k < 4; ++k) {
            const int d    = d0 + k;
            const int lanev = (d & 31) + 32 * hiv;
            short4v w;
            w[0] = f2bf(r0[k]); w[1] = f2bf(r1[k]);
            w[2] = f2bf(r2[k]); w[3] = f2bf(r3[k]);
            *reinterpret_cast<short4v*>(
                vt + (((d >> 5) * 4 + ks) * 64 + lanev) * 8 + j0) = w;
        }
    }
}

// ------------- attn: 8 waves = 4 qsub(32 q-rows) x 2 KV halves --------------
__global__ __launch_bounds__(512) void attn_fwd_kernel(
    const float* __restrict__ Q,
    const short* __restrict__ Kf,
    const short* __restrict__ Vf,
    const int* __restrict__ valid_lens,
    float* __restrict__ O)
{
    __shared__ float  mrg[4][2048];        // halves merge (32 KB)
    __shared__ float2 mlb[4][32];

    const int tid  = threadIdx.x;
    const int wave = tid >> 6;
    const int lane = tid & 63;
    const int l31  = lane & 31;
    const int hi   = lane >> 5;
    const int h    = wave >> 2;            // KV half
    const int qsub = wave & 3;             // q sub-tile (32 rows)

    const int b  = blockIdx.x & 15;        // batch's 16 blocks -> same XCD L2
    const int qt = blockIdx.x >> 4;
    const int qbase = qt * 128 + qsub * 32;

    const int vlen  = valid_lens[b];
    const int nkv   = (vlen == 0) ? NKV : vlen;
    const int tiles = (nkv + KVB - 1) / KVB;
    const int nh = (tiles + 1 - h) >> 1;   // my half's tiles (interleaved)

    // Q B-fragments (scale folded): lane col q=l31, k-elems d = kk*16+hi*8+j
    const float* Qb = Q + ((size_t)b * NQ + qbase + l31) * DH;
    short8 qfrag[4];
#pragma unroll
    for (int kk = 0; kk < 4; ++kk) {
        const float* p = Qb + kk * 16 + hi * 8;
        float4v a = *reinterpret_cast<const float4v*>(p);
        float4v c = *reinterpret_cast<const float4v*>(p + 4);
#pragma unroll
        for (int j = 0; j < 4; ++j) { a[j] *= SCALE_LOG2; c[j] *= SCALE_LOG2; }
        qfrag[kk] = cvt8(a, c);
    }

    const short* Kfb = Kf + (size_t)b * NTILES * TILE_ELEMS + lane * 8;
    const short* Vfb = Vf + (size_t)b * NTILES * TILE_ELEMS + lane * 8;

    auto load_k = [&](short8 (&kf)[8], int tile) {
        const short* p = Kfb + (size_t)tile * TILE_ELEMS;
#pragma unroll
        for (int i = 0; i < 8; ++i)
            kf[i] = *reinterpret_cast<const short8*>(p + i * 512);
    };

    // two independent accumulator sets: even tiles -> A, odd -> B.
    // both always in the same running-max scale; combined by addition.
    f32x16 acc_oA[2], acc_oB[2];
#pragma unroll
    for (int t = 0; t < 2; ++t)
#pragma unroll
        for (int r = 0; r < 16; ++r) { acc_oA[t][r] = 0.f; acc_oB[t][r] = 0.f; }
    float m = -INFINITY, lsum = 0.f;

    short8 kf0[8], kf1[8];

    auto body = [&](short8 (&kc)[8], short8 (&kn)[8], f32x16 (&am)[2], int it) {
        const int tile = 2 * it + h;

        // V fragments: body-local => independent across unrolled bodies
        short8 vfr[8];
        {
            const short* p = Vfb + (size_t)tile * TILE_ELEMS;
#pragma unroll
            for (int i = 0; i < 8; ++i)
                vfr[i] = *reinterpret_cast<const short8*>(p + i * 512);
        }

        // ---- S^T = K Q^T: lane owns q=l31, kv = 32s + (r&3)+8(r>>2)+4hi ----
        f32x16 acs[2];
#pragma unroll
        for (int s = 0; s < 2; ++s)
#pragma unroll
            for (int r = 0; r < 16; ++r) acs[s][r] = 0.f;
        __builtin_amdgcn_s_setprio(1);
#pragma unroll
        for (int s = 0; s < 2; ++s)
#pragma unroll
            for (int kk = 0; kk < 4; ++kk)
                acs[s] = __builtin_amdgcn_mfma_f32_32x32x16_bf16(
                    kc[s * 4 + kk], qfrag[kk], acs[s], 0, 0, 0);
        __builtin_amdgcn_s_setprio(0);

        if (it + 1 < nh) load_k(kn, 2 * (it + 1) + h);  // prefetch next K

        // ---- mask, skipped for fully-valid tiles (wave-uniform) ----
        if (vlen < (tile + 1) * KVB) {
            const int kvb0 = tile * KVB + 4 * hi;
#pragma unroll
            for (int s = 0; s < 2; ++s) {
                const int vlim = vlen - (kvb0 + s * 32);
#pragma unroll
                for (int r = 0; r < 16; ++r) {
                    const int rc = (r & 3) + 8 * (r >> 2);
                    acs[s][r] = (rc < vlim) ? acs[s][r] : NEG_INF;
                }
            }
        }

        // ---- row max: depth-5 tree + 1 shuffle ----
        float mx[8];
#pragma unroll
        for (int r = 0; r < 8; ++r)
            mx[r] = fmaxf(fmaxf(acs[0][r], acs[0][r + 8]),
                          fmaxf(acs[1][r], acs[1][r + 8]));
#pragma unroll
        for (int d = 4; d; d >>= 1)
#pragma unroll
            for (int r = 0; r < d; ++r) mx[r] = fmaxf(mx[r], mx[r + d]);
        float x = mx[0];
        x = fmaxf(x, __shfl_xor(x, 32, 64));

        // ---- T13 defer-max (rescale BOTH accumulator sets; rare) ----
        float mn = m;
        if (!__all(x <= m + 8.f)) {
            mn = fmaxf(m, x);
            const float alpha = fexp2(m - mn);   // m=-inf first -> 0
            m = mn;
            lsum *= alpha;
#pragma unroll
            for (int r = 0; r < 16; ++r) {
                const int rc = (r & 3) + 8 * (r >> 2);
                const float ar = __shfl(alpha, rc + 4 * hi, 64);
                acc_oA[0][r] *= ar; acc_oA[1][r] *= ar;
                acc_oB[0][r] *= ar; acc_oB[1][r] *= ar;
            }
        }

        // ---- P = 2^(s - mn); sum as tree + 1 shuffle ----
#pragma unroll
        for (int s = 0; s < 2; ++s)
#pragma unroll
            for (int r = 0; r < 16; ++r) acs[s][r] = fexp2(acs[s][r] - mn);
        float sm[8];
#pragma unroll
        for (int r = 0; r < 8; ++r)
            sm[r] = (acs[0][r] + acs[0][r + 8]) + (acs[1][r] + acs[1][r + 8]);
#pragma unroll
        for (int d = 4; d; d >>= 1)
#pragma unroll
            for (int r = 0; r < d; ++r) sm[r] += sm[r + d];
        float rs = sm[0];
        rs += __shfl_xor(rs, 32, 64);
        lsum += rs;

        // ---- P -> bf16 packs (16 cvt_pk) ----
        unsigned pk[2][4][2];
#pragma unroll
        for (int s = 0; s < 2; ++s)
#pragma unroll
            for (int be = 0; be < 4; ++be)
#pragma unroll
                for (int c = 0; c < 2; ++c)
                    asm("v_cvt_pk_bf16_f32 %0, %1, %2"
                        : "=v"(pk[s][be][c])
                        : "v"(acs[s][4 * be + 2 * c]),
                          "v"(acs[s][4 * be + 2 * c + 1]));

        // ---- O(me) += P V: 8 permlane32_swap build A-frags in-register ----
        __builtin_amdgcn_s_setprio(1);
#pragma unroll
        for (int ks = 0; ks < 4; ++ks) {
            const int s = ks >> 1, g = ks & 1;
            unsigned w0 = pk[s][2 * g][0], w2 = pk[s][2 * g + 1][0];
            unsigned w1 = pk[s][2 * g][1], w3 = pk[s][2 * g + 1][1];
            asm("v_permlane32_swap_b32 %0, %1" : "+v"(w0), "+v"(w2));
            asm("v_permlane32_swap_b32 %0, %1" : "+v"(w1), "+v"(w3));
            union { unsigned u[4]; short8 s8; } pf;
            pf.u[0] = w0; pf.u[1] = w1; pf.u[2] = w2; pf.u[3] = w3;
#pragma unroll
            for (int t = 0; t < 2; ++t)
                am[t] = __builtin_amdgcn_mfma_f32_32x32x16_bf16(
                    pf.s8, vfr[t * 4 + ks], am[t], 0, 0, 0);
        }
        __builtin_amdgcn_s_setprio(0);
    };

    if (nh > 0) load_k(kf0, h);
    int it = 0;
    for (; it + 1 < nh; it += 2) {         // A/B alternate: independent chains
        body(kf0, kf1, acc_oA, it);
        body(kf1, kf0, acc_oB, it + 1);
    }
    if (it < nh) body(kf0, kf1, acc_oA, it);

    // combine the two chains (same scale)
#pragma unroll
    for (int t = 0; t < 2; ++t)
#pragma unroll
        for (int r = 0; r < 16; ++r) acc_oA[t][r] += acc_oB[t][r];

    // ---- merge the two KV halves; h==0 writes output ----
    if (h == 1) {
#pragma unroll
        for (int t = 0; t < 2; ++t)
#pragma unroll
            for (int r = 0; r < 16; ++r)
                mrg[qsub][(t * 16 + r) * 64 + lane] = acc_oA[t][r];
        if (lane < 32) mlb[qsub][lane] = float2{m, lsum};
    }
    __syncthreads();
    if (h == 0) {
        const float2 o1 = mlb[qsub][l31];
        const float m1 = o1.x, l1 = o1.y;
        const float M  = (l1 > 0.f) ? fmaxf(m, m1) : m;
        const float w0 = fexp2(m - M);
        const float w1 = (l1 > 0.f) ? fexp2(m1 - M) : 0.f;
        const float L  = lsum * w0 + l1 * w1;
        const float a0 = w0 / L, a1 = w1 / L;
        float* Ob = O + ((size_t)b * NQ + qbase) * DH;
#pragma unroll
        for (int r = 0; r < 16; ++r) {
            const int rc = (r & 3) + 8 * (r >> 2);
            const float a0r = __shfl(a0, rc + 4 * hi, 64);
            const float a1r = __shfl(a1, rc + 4 * hi, 64);
#pragma unroll
            for (int t = 0; t < 2; ++t) {
                const float oh = mrg[qsub][(t * 16 + r) * 64 + lane];
                Ob[(size_t)(rc + 4 * hi) * DH + t * 32 + l31] =
                    acc_oA[t][r] * a0r + oh * a1r;
            }
        }
    }
}

extern "C" void kernel_launch(void* const* d_in, const int* in_sizes, int n_in,
                              void* d_out, int out_size, void* d_ws, size_t ws_size,
                              hipStream_t stream) {
    const float* Q = (const float*)d_in[0];
    const float* K = (const float*)d_in[1];
    const float* V = (const float*)d_in[2];
    const int* vl  = (const int*)d_in[3];
    float* Out     = (float*)d_out;

    short* Kws = (short*)d_ws;
    short* Vws = Kws + (size_t)BATCH * NTILES * TILE_ELEMS;

    prep_kernel<<<dim3(BATCH * NTILES), dim3(256), 0, stream>>>(K, V, vl, Kws, Vws);
    attn_fwd_kernel<<<dim3(BATCH * (NQ / 128)), dim3(512), 0, stream>>>(
        Q, Kws, Vws, vl, Out);
}